// Round 1
// baseline (423.860 us; speedup 1.0000x reference)
//
#include <hip/hip_runtime.h>
#include <cstddef>

#define NN   50000
#define KNB  32

__device__ __forceinline__ void ce(float& a, float& b) {
  float lo = fminf(a, b);
  float hi = fmaxf(a, b);
  a = lo;
  b = hi;
}

// Batcher odd-even mergesort, 32 elements, fully unrolled (compile-time
// constant indices -> stays in VGPRs). Only v[15] is consumed by callers,
// so the compiler prunes the cone of influence (dead min/max removed).
__device__ __forceinline__ void sort32(float (&v)[32]) {
  #pragma unroll
  for (int p = 1; p < 32; p <<= 1) {
    #pragma unroll
    for (int k = p; k >= 1; k >>= 1) {
      #pragma unroll
      for (int j = k & (p - 1); j + k < 32; j += 2 * k) {
        #pragma unroll
        for (int i = 0; i < k; ++i) {
          if (i + j + k < 32) {
            if ((i + j) / (2 * p) == (i + j + k) / (2 * p)) {
              ce(v[i + j], v[i + j + k]);
            }
          }
        }
      }
    }
  }
}

// ---------------- GEMM1: C[M,128] = A[M,512] @ B[512,128] + bias ----------
// fp32 vector-ALU GEMM (no fp32 MFMA on CDNA4). Tile 64x128, BK=32,
// 128 threads, 8x8 per thread.
__global__ __launch_bounds__(128) void gemm1(const float* __restrict__ A,
                                             const float* __restrict__ B,
                                             const float* __restrict__ bias,
                                             float* __restrict__ C, int M) {
  constexpr int K = 512, BN = 128, BM = 64, BK = 32, TM = 8, TN = 8;
  __shared__ float As[BM][BK + 1];   // +1 pad: a-reads land on distinct banks
  __shared__ float Bs[BK][BN];
  const int tid  = threadIdx.x;
  const int tx   = tid & 15;         // 0..15  (col group of 8)
  const int ty   = tid >> 4;         // 0..7   (row group of 8)
  const int row0 = blockIdx.x * BM;

  float acc[TM][TN] = {};

  const int ar   = tid >> 1;         // 0..63  A-stage row
  const int ah   = (tid & 1) * 16;   // half-row offset
  const int bkr  = tid >> 2;         // 0..31  B-stage k-row
  const int bseg = (tid & 3) * 32;   // 32-float segment

  for (int k0 = 0; k0 < K; k0 += BK) {
    // stage A (64x32): 16 floats/thread, float4 global loads
    {
      const int grow = row0 + ar;
      const float* asrc = A + (size_t)grow * K + k0 + ah;
      float4 t[4];
      #pragma unroll
      for (int q = 0; q < 4; ++q)
        t[q] = (grow < M) ? *(const float4*)(asrc + 4 * q)
                          : make_float4(0.f, 0.f, 0.f, 0.f);
      #pragma unroll
      for (int q = 0; q < 4; ++q) {
        As[ar][ah + 4 * q + 0] = t[q].x;
        As[ar][ah + 4 * q + 1] = t[q].y;
        As[ar][ah + 4 * q + 2] = t[q].z;
        As[ar][ah + 4 * q + 3] = t[q].w;
      }
    }
    // stage B (32x128): 32 floats/thread, float4 in and out
    {
      const float* bsrc = B + (size_t)(k0 + bkr) * BN + bseg;
      #pragma unroll
      for (int q = 0; q < 8; ++q)
        *(float4*)&Bs[bkr][bseg + 4 * q] = *(const float4*)(bsrc + 4 * q);
    }
    __syncthreads();

    #pragma unroll 4
    for (int kk = 0; kk < BK; ++kk) {
      float a[TM];
      #pragma unroll
      for (int i = 0; i < TM; ++i) a[i] = As[ty * TM + i][kk];
      const float4 b0 = *(const float4*)&Bs[kk][tx * TN];
      const float4 b1 = *(const float4*)&Bs[kk][tx * TN + 4];
      const float b[TN] = {b0.x, b0.y, b0.z, b0.w, b1.x, b1.y, b1.z, b1.w};
      #pragma unroll
      for (int i = 0; i < TM; ++i)
        #pragma unroll
        for (int j = 0; j < TN; ++j)
          acc[i][j] += a[i] * b[j];
    }
    __syncthreads();
  }

  // epilogue: + bias, float4 stores
  float bv[TN];
  {
    const float4 u0 = *(const float4*)(bias + tx * TN);
    const float4 u1 = *(const float4*)(bias + tx * TN + 4);
    bv[0] = u0.x; bv[1] = u0.y; bv[2] = u0.z; bv[3] = u0.w;
    bv[4] = u1.x; bv[5] = u1.y; bv[6] = u1.z; bv[7] = u1.w;
  }
  #pragma unroll
  for (int i = 0; i < TM; ++i) {
    const int grow = row0 + ty * TM + i;
    if (grow < M) {
      float4 r0 = make_float4(acc[i][0] + bv[0], acc[i][1] + bv[1],
                              acc[i][2] + bv[2], acc[i][3] + bv[3]);
      float4 r1 = make_float4(acc[i][4] + bv[4], acc[i][5] + bv[5],
                              acc[i][6] + bv[6], acc[i][7] + bv[7]);
      *(float4*)(C + (size_t)grow * BN + tx * TN)     = r0;
      *(float4*)(C + (size_t)grow * BN + tx * TN + 4) = r1;
    }
  }
}

// ---------------- GEMM2: C[M,64] = A[M,128] @ B[128,64] + bias ------------
// Tile 128x64, BK=32, 128 threads, 8x8 per thread.
__global__ __launch_bounds__(128) void gemm2(const float* __restrict__ A,
                                             const float* __restrict__ B,
                                             const float* __restrict__ bias,
                                             float* __restrict__ C, int M) {
  constexpr int K = 128, BN = 64, BM = 128, BK = 32, TM = 8, TN = 8;
  __shared__ float As[BM][BK + 1];
  __shared__ float Bs[BK][BN];
  const int tid  = threadIdx.x;
  const int tx   = tid & 7;          // 0..7
  const int ty   = tid >> 3;         // 0..15
  const int row0 = blockIdx.x * BM;

  float acc[TM][TN] = {};

  const int bkr  = tid >> 2;         // 0..31
  const int bseg = (tid & 3) * 16;   // 16-float segment

  for (int k0 = 0; k0 < K; k0 += BK) {
    // stage A (128x32): one full k-chunk row per thread
    {
      const int grow = row0 + tid;
      const float* asrc = A + (size_t)grow * K + k0;
      float4 t[8];
      #pragma unroll
      for (int q = 0; q < 8; ++q)
        t[q] = (grow < M) ? *(const float4*)(asrc + 4 * q)
                          : make_float4(0.f, 0.f, 0.f, 0.f);
      #pragma unroll
      for (int q = 0; q < 8; ++q) {
        As[tid][4 * q + 0] = t[q].x;
        As[tid][4 * q + 1] = t[q].y;
        As[tid][4 * q + 2] = t[q].z;
        As[tid][4 * q + 3] = t[q].w;
      }
    }
    // stage B (32x64): 16 floats/thread
    {
      const float* bsrc = B + (size_t)(k0 + bkr) * BN + bseg;
      #pragma unroll
      for (int q = 0; q < 4; ++q)
        *(float4*)&Bs[bkr][bseg + 4 * q] = *(const float4*)(bsrc + 4 * q);
    }
    __syncthreads();

    #pragma unroll 4
    for (int kk = 0; kk < BK; ++kk) {
      float a[TM];
      #pragma unroll
      for (int i = 0; i < TM; ++i) a[i] = As[ty * TM + i][kk];
      const float4 b0 = *(const float4*)&Bs[kk][tx * TN];
      const float4 b1 = *(const float4*)&Bs[kk][tx * TN + 4];
      const float b[TN] = {b0.x, b0.y, b0.z, b0.w, b1.x, b1.y, b1.z, b1.w};
      #pragma unroll
      for (int i = 0; i < TM; ++i)
        #pragma unroll
        for (int j = 0; j < TN; ++j)
          acc[i][j] += a[i] * b[j];
    }
    __syncthreads();
  }

  float bv[TN];
  {
    const float4 u0 = *(const float4*)(bias + tx * TN);
    const float4 u1 = *(const float4*)(bias + tx * TN + 4);
    bv[0] = u0.x; bv[1] = u0.y; bv[2] = u0.z; bv[3] = u0.w;
    bv[4] = u1.x; bv[5] = u1.y; bv[6] = u1.z; bv[7] = u1.w;
  }
  #pragma unroll
  for (int i = 0; i < TM; ++i) {
    const int grow = row0 + ty * TM + i;
    if (grow < M) {
      float4 r0 = make_float4(acc[i][0] + bv[0], acc[i][1] + bv[1],
                              acc[i][2] + bv[2], acc[i][3] + bv[3]);
      float4 r1 = make_float4(acc[i][4] + bv[4], acc[i][5] + bv[5],
                              acc[i][6] + bv[6], acc[i][7] + bv[7]);
      *(float4*)(C + (size_t)grow * BN + tx * TN)     = r0;
      *(float4*)(C + (size_t)grow * BN + tx * TN + 4) = r1;
    }
  }
}

// ------------- Median over 32 neighbor rows (layer 1, D=128) + ReLU -------
// One block (128 threads) per node; lane = feature. 32 values in VGPRs,
// sorting network, take sorted[15] (lower median, matches jnp.sort[:,15]).
__global__ __launch_bounds__(128) void median_relu1(const float* __restrict__ H,
                                                    const int* __restrict__ nb,
                                                    float* __restrict__ O) {
  const int node = blockIdx.x;
  const int f    = threadIdx.x;          // 0..127
  const int* nrow = nb + (size_t)node * KNB;
  float v[32];
  #pragma unroll
  for (int j = 0; j < KNB; ++j) {
    const int idx = nrow[j];             // wave-uniform -> scalar loads
    v[j] = H[(size_t)idx * 128 + f];     // coalesced 256B/wave
  }
  sort32(v);
  O[(size_t)node * 128 + f] = fmaxf(v[15], 0.f);
}

// ------------- Median over 32 neighbor rows (layer 2, D=64) ---------------
// Two nodes per 128-thread block (one per wave).
__global__ __launch_bounds__(128) void median2(const float* __restrict__ H,
                                               const int* __restrict__ nb,
                                               float* __restrict__ O) {
  const int node = blockIdx.x * 2 + (threadIdx.x >> 6);
  const int f    = threadIdx.x & 63;
  const int* nrow = nb + (size_t)node * KNB;
  float v[32];
  #pragma unroll
  for (int j = 0; j < KNB; ++j) {
    const int idx = nrow[j];
    v[j] = H[(size_t)idx * 64 + f];
  }
  sort32(v);
  O[(size_t)node * 64 + f] = v[15];
}

extern "C" void kernel_launch(void* const* d_in, const int* in_sizes, int n_in,
                              void* d_out, int out_size, void* d_ws, size_t ws_size,
                              hipStream_t stream) {
  const float* feat = (const float*)d_in[0];   // [50000,512]
  const float* W1   = (const float*)d_in[1];   // [512,128]
  const float* b1   = (const float*)d_in[2];   // [128]
  const float* W2   = (const float*)d_in[3];   // [128,64]
  const float* b2   = (const float*)d_in[4];   // [64]
  const int*   nb   = (const int*)d_in[5];     // [50000,32]
  float* out = (float*)d_out;                  // [50000,64]

  float* h1   = (float*)d_ws;                  // 50000*128 = 25.6 MB
  float* med1 = h1 + (size_t)NN * 128;         // 50000*128 = 25.6 MB
  float* h2   = h1;                            // reuse h1 region (dead)

  gemm1<<<dim3((NN + 63) / 64), dim3(128), 0, stream>>>(feat, W1, b1, h1, NN);
  median_relu1<<<dim3(NN), dim3(128), 0, stream>>>(h1, nb, med1);
  gemm2<<<dim3((NN + 127) / 128), dim3(128), 0, stream>>>(med1, W2, b2, h2, NN);
  median2<<<dim3(NN / 2), dim3(128), 0, stream>>>(h2, nb, out);
}